// Round 9
// baseline (588.730 us; speedup 1.0000x reference)
//
#include <hip/hip_runtime.h>
#include <math.h>

#define NC 6
#define NS 500
#define HWD 768
#define NP (HWD*HWD)
#define EPSF 1e-5f
#define NITER 5
#define TBL (NS*NC)

// ---------------------------------------------------------------------------
// mix_kernel: M = compat @ (spatial_w + bilateral_w)
// ---------------------------------------------------------------------------
__global__ void mix_kernel(const float* __restrict__ sw, const float* __restrict__ bw,
                           const float* __restrict__ cm, float* __restrict__ M) {
    int i = threadIdx.x;
    if (i < NC * NC) {
        int c = i / NC, k = i % NC;
        float acc = 0.f;
        #pragma unroll
        for (int j = 0; j < NC; j++) acc += cm[c * NC + j] * (sw[j * NC + k] + bw[j * NC + k]);
        M[i] = acc;
    }
}

// ---------------------------------------------------------------------------
// prep: sm0 = softmax(unaries) pixel-major;  seg[p] = sp_map[(p%768)*768+p/768]
// ---------------------------------------------------------------------------
__global__ __launch_bounds__(256) void prep_kernel(const float* __restrict__ unaries,
                                                   const int* __restrict__ sp_map,
                                                   float* __restrict__ sm,
                                                   int* __restrict__ seg) {
    int p = blockIdx.x * blockDim.x + threadIdx.x;
    if (p >= NP) return;
    int h = p / HWD;
    int w = p - h * HWD;
    seg[p] = sp_map[w * HWD + h];

    const float2* u2 = (const float2*)(unaries + (size_t)p * NC);
    float2 a0 = u2[0], a1 = u2[1], a2 = u2[2];
    float v[NC] = {a0.x, a0.y, a1.x, a1.y, a2.x, a2.y};
    float m = v[0];
    #pragma unroll
    for (int c = 1; c < NC; c++) m = fmaxf(m, v[c]);
    float s = 0.f;
    #pragma unroll
    for (int c = 0; c < NC; c++) { v[c] = expf(v[c] - m); s += v[c]; }
    float inv = 1.f / s;
    float2* o2 = (float2*)(sm + (size_t)p * NC);
    o2[0] = make_float2(v[0] * inv, v[1] * inv);
    o2[1] = make_float2(v[2] * inv, v[3] * inv);
    o2[2] = make_float2(v[4] * inv, v[5] * inv);
}

// ---------------------------------------------------------------------------
// one-time counting sort of pixels by segment id
// ---------------------------------------------------------------------------
__global__ __launch_bounds__(256) void hist_kernel(const int* __restrict__ seg,
                                                   int* __restrict__ cnt) {
    int p = blockIdx.x * blockDim.x + threadIdx.x;
    if (p >= NP) return;
    int s = seg[p];
    if (s >= 0 && s < NS) atomicAdd(&cnt[s], 1);
}

__global__ __launch_bounds__(512) void prefix_kernel(int* __restrict__ starts,
                                                     int* __restrict__ cursor) {
    __shared__ int A[512], Bb[512];
    int tid = threadIdx.x;
    int own = (tid < NS) ? starts[tid] : 0;
    A[tid] = own;
    __syncthreads();
    int* src = A; int* dst = Bb;
    for (int off = 1; off < 512; off <<= 1) {
        int v = src[tid];
        if (tid >= off) v += src[tid - off];
        dst[tid] = v;
        __syncthreads();
        int* t = src; src = dst; dst = t;
    }
    int incl = src[tid];
    int excl = incl - own;
    if (tid < NS) { starts[tid] = excl; cursor[tid] = excl; }
    if (tid == NS - 1) starts[NS] = incl;
}

__global__ __launch_bounds__(256) void scatter_kernel(const int* __restrict__ seg,
                                                      int* __restrict__ cursor,
                                                      int* __restrict__ perm) {
    int p = blockIdx.x * blockDim.x + threadIdx.x;
    if (p >= NP) return;
    int s = seg[p];
    if (s >= 0 && s < NS) {
        int idx = atomicAdd(&cursor[s], 1);
        perm[idx] = p;
    }
}

// ---------------------------------------------------------------------------
// k2: one block per segment; register accumulation, shfl reduce, NO atomics
// ---------------------------------------------------------------------------
__global__ __launch_bounds__(256) void k2_accum(const float* __restrict__ sm,
                                                const int* __restrict__ perm,
                                                const int* __restrict__ starts,
                                                float* __restrict__ B) {
    int s = blockIdx.x;
    int lo = starts[s], hi = starts[s + 1];
    int tid = threadIdx.x;
    float asp[NC] = {0.f, 0.f, 0.f, 0.f, 0.f, 0.f};
    float aco[NC] = {0.f, 0.f, 0.f, 0.f, 0.f, 0.f};

    for (int i = lo + tid; i < hi; i += 256) {
        int p = perm[i];
        const float2* s2 = (const float2*)(sm + (size_t)p * NC);
        float2 a0 = s2[0], a1 = s2[1], a2 = s2[2];
        float v[NC] = {a0.x, a0.y, a1.x, a1.y, a2.x, a2.y};
        float mx = v[0];
        #pragma unroll
        for (int c = 1; c < NC; c++) mx = fmaxf(mx, v[c]);
        float maxq = mx + EPSF;
        #pragma unroll
        for (int c = 0; c < NC; c++) {
            asp[c] += logf(v[c] + EPSF);
            float a = v[c] + EPSF + maxq - ((v[c] == mx) ? v[c] : 0.f);
            aco[c] += logf(a);
        }
    }
    // wave reduction (64 lanes)
    #pragma unroll
    for (int c = 0; c < NC; c++) {
        #pragma unroll
        for (int off = 1; off < 64; off <<= 1) {
            asp[c] += __shfl_xor(asp[c], off, 64);
            aco[c] += __shfl_xor(aco[c], off, 64);
        }
    }
    __shared__ float red[4][2 * NC];
    int wid = tid >> 6, lane = tid & 63;
    if (lane == 0) {
        #pragma unroll
        for (int c = 0; c < NC; c++) { red[wid][c] = asp[c]; red[wid][NC + c] = aco[c]; }
    }
    __syncthreads();
    if (tid < 2 * NC) {
        float sum = red[0][tid] + red[1][tid] + red[2][tid] + red[3][tid];
        if (tid < NC) B[s * NC + tid] = sum;
        else          B[TBL + s * NC + (tid - NC)] = sum;
    }
}

// ---------------------------------------------------------------------------
// k3: fused per-pixel update + softmax for next iteration
// ---------------------------------------------------------------------------
__global__ __launch_bounds__(256) void k3_update(const float* __restrict__ unaries,
                                                 const float* __restrict__ sm,
                                                 const int* __restrict__ seg,
                                                 const float* __restrict__ B,
                                                 const float* __restrict__ low_w,
                                                 const float* __restrict__ high_w,
                                                 const float* __restrict__ M,
                                                 float* __restrict__ sm_next,
                                                 float* __restrict__ out,
                                                 int writeOut) {
    __shared__ float sM[NC * NC];
    __shared__ float slw[2 * NC];
    __shared__ float shw[2];
    if (threadIdx.x < NC * NC) sM[threadIdx.x] = M[threadIdx.x];
    if (threadIdx.x < 2 * NC) slw[threadIdx.x] = low_w[threadIdx.x];
    if (threadIdx.x < 2) shw[threadIdx.x] = high_w[threadIdx.x];
    __syncthreads();

    int stride = gridDim.x * blockDim.x;
    for (int p = blockIdx.x * blockDim.x + threadIdx.x; p < NP; p += stride) {
        const float2* s2 = (const float2*)(sm + (size_t)p * NC);
        float2 a0 = s2[0], a1 = s2[1], a2 = s2[2];
        float v[NC] = {a0.x, a0.y, a1.x, a1.y, a2.x, a2.y};

        int sg = seg[p];
        bool inr = (sg >= 0 && sg < NS);
        int sc = inr ? sg : (sg < 0 ? 0 : NS - 1);
        float fin = inr ? 1.f : 0.f;

        float mx = v[0];
        #pragma unroll
        for (int c = 1; c < NC; c++) mx = fmaxf(mx, v[c]);
        float maxq = mx + EPSF;

        const float2* bsp2 = (const float2*)(B + (size_t)sc * NC);
        const float2* bco2 = (const float2*)(B + TBL + (size_t)sc * NC);
        float2 p0 = bsp2[0], p1 = bsp2[1], p2 = bsp2[2];
        float2 c0 = bco2[0], c1 = bco2[1], c2 = bco2[2];
        float psp[NC] = {p0.x, p0.y, p1.x, p1.y, p2.x, p2.y};
        float pio[NC] = {c0.x, c0.y, c1.x, c1.y, c2.x, c2.y};

        float cont[NC];
        #pragma unroll
        for (int c = 0; c < NC; c++) {
            float ps = psp[c] * fin;
            float pi = pio[c] * fin;
            float a = v[c] + EPSF + maxq - ((v[c] == mx) ? v[c] : 0.f);
            float qvs = a * fin;
            qvs += (qvs == 0.f) ? 1.f : 0.f;
            float qmod = v[c] + ((v[c] == 0.f) ? 1.f : 0.f);
            float ftsp = expf(ps - logf(qmod + EPSF));
            float spu = slw[c] * ftsp + shw[0] * (1.f - ftsp);
            float ftc = expf(pi - logf(qvs + EPSF));
            float cu = slw[NC + c] * ftc + shw[1] * (1.f - ftc);
            cont[c] = spu + cu;
        }

        const float2* u2 = (const float2*)(unaries + (size_t)p * NC);
        float2 u0 = u2[0], u1 = u2[1], u2v = u2[2];
        float uu[NC] = {u0.x, u0.y, u1.x, u1.y, u2v.x, u2v.y};

        float qn[NC];
        #pragma unroll
        for (int c = 0; c < NC; c++) {
            float pw = 0.f;
            #pragma unroll
            for (int k = 0; k < NC; k++) pw += sM[c * NC + k] * v[k];
            qn[c] = uu[c] - pw - cont[c];
        }

        if (writeOut) {
            float2* o2 = (float2*)(out + (size_t)p * NC);
            o2[0] = make_float2(qn[0], qn[1]);
            o2[1] = make_float2(qn[2], qn[3]);
            o2[2] = make_float2(qn[4], qn[5]);
        } else {
            float m2 = qn[0];
            #pragma unroll
            for (int c = 1; c < NC; c++) m2 = fmaxf(m2, qn[c]);
            float ssum = 0.f;
            #pragma unroll
            for (int c = 0; c < NC; c++) { qn[c] = expf(qn[c] - m2); ssum += qn[c]; }
            float inv = 1.f / ssum;
            float2* o2 = (float2*)(sm_next + (size_t)p * NC);
            o2[0] = make_float2(qn[0] * inv, qn[1] * inv);
            o2[1] = make_float2(qn[2] * inv, qn[3] * inv);
            o2[2] = make_float2(qn[4] * inv, qn[5] * inv);
        }
    }
}

extern "C" void kernel_launch(void* const* d_in, const int* in_sizes, int n_in,
                              void* d_out, int out_size, void* d_ws, size_t ws_size,
                              hipStream_t stream) {
    const float* unaries = (const float*)d_in[0];
    // d_in[1] = rgb (unused: high_dim_filter replaced by identity)
    const int* sp_map   = (const int*)d_in[2];
    const float* sw     = (const float*)d_in[3];
    const float* bw     = (const float*)d_in[4];
    const float* cm     = (const float*)d_in[5];
    const float* lw     = (const float*)d_in[6];
    const float* hw     = (const float*)d_in[7];
    float* out = (float*)d_out;

    float* smA    = (float*)d_ws;                       // NP*NC floats
    float* smB    = smA + (size_t)NP * NC;              // NP*NC floats
    float* B      = smB + (size_t)NP * NC;              // 2*TBL floats
    float* M      = B + 2 * TBL;                        // 36 floats
    int*   seg    = (int*)(M + NC * NC);                // NP ints
    int*   perm   = seg + NP;                           // NP ints
    int*   starts = perm + NP;                          // NS+1 ints
    int*   cursor = starts + NS + 1;                    // NS ints

    hipMemsetAsync(starts, 0, (NS + 1) * sizeof(int), stream);
    mix_kernel<<<1, 64, 0, stream>>>(sw, bw, cm, M);
    prep_kernel<<<(NP + 255) / 256, 256, 0, stream>>>(unaries, sp_map, smA, seg);
    hist_kernel<<<(NP + 255) / 256, 256, 0, stream>>>(seg, starts);
    prefix_kernel<<<1, 512, 0, stream>>>(starts, cursor);
    scatter_kernel<<<(NP + 255) / 256, 256, 0, stream>>>(seg, cursor, perm);

    float* cur = smA;
    float* nxt = smB;
    for (int it = 0; it < NITER; it++) {
        k2_accum<<<NS, 256, 0, stream>>>(cur, perm, starts, B);
        k3_update<<<2048, 256, 0, stream>>>(unaries, cur, seg, B, lw, hw, M,
                                            nxt, out, (it == NITER - 1) ? 1 : 0);
        float* t = cur; cur = nxt; nxt = t;
    }
}

// Round 10
// 251.472 us; speedup vs baseline: 2.3411x; 2.3411x over previous
//
#include <hip/hip_runtime.h>
#include <math.h>

#define NC 6
#define NS 500
#define HWD 768
#define NP (HWD*HWD)
#define NBLK (NP/256)        // 2304 blocks of 256 pixels (exact)
#define EPSF 1e-5f
#define NITER 5
#define TBL (NS*NC)

// ---------------------------------------------------------------------------
// mix_kernel: M = compat @ (spatial_w + bilateral_w)
// ---------------------------------------------------------------------------
__global__ void mix_kernel(const float* __restrict__ sw, const float* __restrict__ bw,
                           const float* __restrict__ cm, float* __restrict__ M) {
    int i = threadIdx.x;
    if (i < NC * NC) {
        int c = i / NC, k = i % NC;
        float acc = 0.f;
        #pragma unroll
        for (int j = 0; j < NC; j++) acc += cm[c * NC + j] * (sw[j * NC + k] + bw[j * NC + k]);
        M[i] = acc;
    }
}

// ---------------------------------------------------------------------------
// prep: sm0 = softmax(unaries) pixel-major;  seg[p] = sp_map[(p%768)*768+p/768]
// ---------------------------------------------------------------------------
__global__ __launch_bounds__(256) void prep_kernel(const float* __restrict__ unaries,
                                                   const int* __restrict__ sp_map,
                                                   float* __restrict__ sm,
                                                   int* __restrict__ seg) {
    int p = blockIdx.x * blockDim.x + threadIdx.x;
    if (p >= NP) return;
    int h = p / HWD;
    int w = p - h * HWD;
    seg[p] = sp_map[w * HWD + h];

    const float2* u2 = (const float2*)(unaries + (size_t)p * NC);
    float2 a0 = u2[0], a1 = u2[1], a2 = u2[2];
    float v[NC] = {a0.x, a0.y, a1.x, a1.y, a2.x, a2.y};
    float m = v[0];
    #pragma unroll
    for (int c = 1; c < NC; c++) m = fmaxf(m, v[c]);
    float s = 0.f;
    #pragma unroll
    for (int c = 0; c < NC; c++) { v[c] = expf(v[c] - m); s += v[c]; }
    float inv = 1.f / s;
    float2* o2 = (float2*)(sm + (size_t)p * NC);
    o2[0] = make_float2(v[0] * inv, v[1] * inv);
    o2[1] = make_float2(v[2] * inv, v[3] * inv);
    o2[2] = make_float2(v[4] * inv, v[5] * inv);
}

// ---------------------------------------------------------------------------
// counting sort, phase A: per-block LDS histogram -> hist[b][s] (plain stores)
// ---------------------------------------------------------------------------
__global__ __launch_bounds__(256) void lhist_kernel(const int* __restrict__ seg,
                                                    int* __restrict__ hist) {
    __shared__ int h[NS];
    int tid = threadIdx.x;
    for (int s = tid; s < NS; s += 256) h[s] = 0;
    __syncthreads();
    int p = blockIdx.x * 256 + tid;
    int s = seg[p];
    if (s >= 0 && s < NS) atomicAdd(&h[s], 1);   // LDS, no return use
    __syncthreads();
    int* row = hist + (size_t)blockIdx.x * NS;
    for (int s = tid; s < NS; s += 256) row[s] = h[s];
}

// ---------------------------------------------------------------------------
// phase B: per-bin exclusive scan over the 2304 block counts (in place)
// grid = NS blocks, 256 threads, 9 elements/thread (2304 = 256*9)
// ---------------------------------------------------------------------------
__global__ __launch_bounds__(256) void colscan_kernel(int* __restrict__ hist,
                                                      int* __restrict__ total) {
    int s = blockIdx.x, tid = threadIdx.x;
    int loc[9];
    int sum = 0;
    #pragma unroll
    for (int j = 0; j < 9; j++) {
        loc[j] = hist[(size_t)(tid * 9 + j) * NS + s];
        sum += loc[j];
    }
    __shared__ int A[256], Bf[256];
    A[tid] = sum;
    __syncthreads();
    int* src = A; int* dst = Bf;
    for (int off = 1; off < 256; off <<= 1) {
        int v = src[tid];
        if (tid >= off) v += src[tid - off];
        dst[tid] = v;
        __syncthreads();
        int* t = src; src = dst; dst = t;
    }
    int incl = src[tid];
    int run = incl - sum;          // exclusive prefix for this thread's chunk
    #pragma unroll
    for (int j = 0; j < 9; j++) {
        int v = loc[j];
        hist[(size_t)(tid * 9 + j) * NS + s] = run;
        run += v;
    }
    if (tid == 255) total[s] = run;
}

// ---------------------------------------------------------------------------
// phase C: exclusive scan over bin totals -> starts[0..NS]
// ---------------------------------------------------------------------------
__global__ __launch_bounds__(512) void binscan_kernel(const int* __restrict__ total,
                                                      int* __restrict__ starts) {
    __shared__ int A[512], Bf[512];
    int tid = threadIdx.x;
    int own = (tid < NS) ? total[tid] : 0;
    A[tid] = own;
    __syncthreads();
    int* src = A; int* dst = Bf;
    for (int off = 1; off < 512; off <<= 1) {
        int v = src[tid];
        if (tid >= off) v += src[tid - off];
        dst[tid] = v;
        __syncthreads();
        int* t = src; src = dst; dst = t;
    }
    int incl = src[tid];
    if (tid < NS) starts[tid] = incl - own;
    if (tid == NS - 1) starts[NS] = incl;
}

// ---------------------------------------------------------------------------
// phase D: scatter via per-block LDS cursors (no global atomics)
// ---------------------------------------------------------------------------
__global__ __launch_bounds__(256) void scatter2_kernel(const int* __restrict__ seg,
                                                       const int* __restrict__ hist,
                                                       const int* __restrict__ starts,
                                                       int* __restrict__ perm) {
    __shared__ int cur[NS];
    int tid = threadIdx.x;
    const int* row = hist + (size_t)blockIdx.x * NS;
    for (int s = tid; s < NS; s += 256) cur[s] = starts[s] + row[s];
    __syncthreads();
    int p = blockIdx.x * 256 + tid;
    int s = seg[p];
    if (s >= 0 && s < NS) {
        int idx = atomicAdd(&cur[s], 1);   // LDS atomic, ~256/block
        perm[idx] = p;
    }
}

// ---------------------------------------------------------------------------
// k2: one block per segment; register accumulation, shfl reduce, NO atomics
// ---------------------------------------------------------------------------
__global__ __launch_bounds__(256) void k2_accum(const float* __restrict__ sm,
                                                const int* __restrict__ perm,
                                                const int* __restrict__ starts,
                                                float* __restrict__ B) {
    int s = blockIdx.x;
    int lo = starts[s], hi = starts[s + 1];
    int tid = threadIdx.x;
    float asp[NC] = {0.f, 0.f, 0.f, 0.f, 0.f, 0.f};
    float aco[NC] = {0.f, 0.f, 0.f, 0.f, 0.f, 0.f};

    for (int i = lo + tid; i < hi; i += 256) {
        int p = perm[i];
        const float2* s2 = (const float2*)(sm + (size_t)p * NC);
        float2 a0 = s2[0], a1 = s2[1], a2 = s2[2];
        float v[NC] = {a0.x, a0.y, a1.x, a1.y, a2.x, a2.y};
        float mx = v[0];
        #pragma unroll
        for (int c = 1; c < NC; c++) mx = fmaxf(mx, v[c]);
        float maxq = mx + EPSF;
        #pragma unroll
        for (int c = 0; c < NC; c++) {
            asp[c] += logf(v[c] + EPSF);
            float a = v[c] + EPSF + maxq - ((v[c] == mx) ? v[c] : 0.f);
            aco[c] += logf(a);
        }
    }
    #pragma unroll
    for (int c = 0; c < NC; c++) {
        #pragma unroll
        for (int off = 1; off < 64; off <<= 1) {
            asp[c] += __shfl_xor(asp[c], off, 64);
            aco[c] += __shfl_xor(aco[c], off, 64);
        }
    }
    __shared__ float red[4][2 * NC];
    int wid = tid >> 6, lane = tid & 63;
    if (lane == 0) {
        #pragma unroll
        for (int c = 0; c < NC; c++) { red[wid][c] = asp[c]; red[wid][NC + c] = aco[c]; }
    }
    __syncthreads();
    if (tid < 2 * NC) {
        float sum = red[0][tid] + red[1][tid] + red[2][tid] + red[3][tid];
        if (tid < NC) B[s * NC + tid] = sum;
        else          B[TBL + s * NC + (tid - NC)] = sum;
    }
}

// ---------------------------------------------------------------------------
// k3: fused per-pixel update + softmax for next iteration
// ---------------------------------------------------------------------------
__global__ __launch_bounds__(256) void k3_update(const float* __restrict__ unaries,
                                                 const float* __restrict__ sm,
                                                 const int* __restrict__ seg,
                                                 const float* __restrict__ B,
                                                 const float* __restrict__ low_w,
                                                 const float* __restrict__ high_w,
                                                 const float* __restrict__ M,
                                                 float* __restrict__ sm_next,
                                                 float* __restrict__ out,
                                                 int writeOut) {
    __shared__ float sM[NC * NC];
    __shared__ float slw[2 * NC];
    __shared__ float shw[2];
    if (threadIdx.x < NC * NC) sM[threadIdx.x] = M[threadIdx.x];
    if (threadIdx.x < 2 * NC) slw[threadIdx.x] = low_w[threadIdx.x];
    if (threadIdx.x < 2) shw[threadIdx.x] = high_w[threadIdx.x];
    __syncthreads();

    int stride = gridDim.x * blockDim.x;
    for (int p = blockIdx.x * blockDim.x + threadIdx.x; p < NP; p += stride) {
        const float2* s2 = (const float2*)(sm + (size_t)p * NC);
        float2 a0 = s2[0], a1 = s2[1], a2 = s2[2];
        float v[NC] = {a0.x, a0.y, a1.x, a1.y, a2.x, a2.y};

        int sg = seg[p];
        bool inr = (sg >= 0 && sg < NS);
        int sc = inr ? sg : (sg < 0 ? 0 : NS - 1);
        float fin = inr ? 1.f : 0.f;

        float mx = v[0];
        #pragma unroll
        for (int c = 1; c < NC; c++) mx = fmaxf(mx, v[c]);
        float maxq = mx + EPSF;

        const float2* bsp2 = (const float2*)(B + (size_t)sc * NC);
        const float2* bco2 = (const float2*)(B + TBL + (size_t)sc * NC);
        float2 p0 = bsp2[0], p1 = bsp2[1], p2 = bsp2[2];
        float2 c0 = bco2[0], c1 = bco2[1], c2 = bco2[2];
        float psp[NC] = {p0.x, p0.y, p1.x, p1.y, p2.x, p2.y};
        float pio[NC] = {c0.x, c0.y, c1.x, c1.y, c2.x, c2.y};

        float cont[NC];
        #pragma unroll
        for (int c = 0; c < NC; c++) {
            float ps = psp[c] * fin;
            float pi = pio[c] * fin;
            float a = v[c] + EPSF + maxq - ((v[c] == mx) ? v[c] : 0.f);
            float qvs = a * fin;
            qvs += (qvs == 0.f) ? 1.f : 0.f;
            float qmod = v[c] + ((v[c] == 0.f) ? 1.f : 0.f);
            float ftsp = expf(ps - logf(qmod + EPSF));
            float spu = slw[c] * ftsp + shw[0] * (1.f - ftsp);
            float ftc = expf(pi - logf(qvs + EPSF));
            float cu = slw[NC + c] * ftc + shw[1] * (1.f - ftc);
            cont[c] = spu + cu;
        }

        const float2* u2 = (const float2*)(unaries + (size_t)p * NC);
        float2 u0 = u2[0], u1 = u2[1], u2v = u2[2];
        float uu[NC] = {u0.x, u0.y, u1.x, u1.y, u2v.x, u2v.y};

        float qn[NC];
        #pragma unroll
        for (int c = 0; c < NC; c++) {
            float pw = 0.f;
            #pragma unroll
            for (int k = 0; k < NC; k++) pw += sM[c * NC + k] * v[k];
            qn[c] = uu[c] - pw - cont[c];
        }

        if (writeOut) {
            float2* o2 = (float2*)(out + (size_t)p * NC);
            o2[0] = make_float2(qn[0], qn[1]);
            o2[1] = make_float2(qn[2], qn[3]);
            o2[2] = make_float2(qn[4], qn[5]);
        } else {
            float m2 = qn[0];
            #pragma unroll
            for (int c = 1; c < NC; c++) m2 = fmaxf(m2, qn[c]);
            float ssum = 0.f;
            #pragma unroll
            for (int c = 0; c < NC; c++) { qn[c] = expf(qn[c] - m2); ssum += qn[c]; }
            float inv = 1.f / ssum;
            float2* o2 = (float2*)(sm_next + (size_t)p * NC);
            o2[0] = make_float2(qn[0] * inv, qn[1] * inv);
            o2[1] = make_float2(qn[2] * inv, qn[3] * inv);
            o2[2] = make_float2(qn[4] * inv, qn[5] * inv);
        }
    }
}

extern "C" void kernel_launch(void* const* d_in, const int* in_sizes, int n_in,
                              void* d_out, int out_size, void* d_ws, size_t ws_size,
                              hipStream_t stream) {
    const float* unaries = (const float*)d_in[0];
    // d_in[1] = rgb (unused: high_dim_filter replaced by identity)
    const int* sp_map   = (const int*)d_in[2];
    const float* sw     = (const float*)d_in[3];
    const float* bw     = (const float*)d_in[4];
    const float* cm     = (const float*)d_in[5];
    const float* lw     = (const float*)d_in[6];
    const float* hw     = (const float*)d_in[7];
    float* out = (float*)d_out;

    float* smA    = (float*)d_ws;                       // NP*NC floats
    float* smB    = smA + (size_t)NP * NC;              // NP*NC floats
    float* B      = smB + (size_t)NP * NC;              // 2*TBL floats
    float* M      = B + 2 * TBL;                        // 36 floats
    int*   seg    = (int*)(M + NC * NC);                // NP ints
    int*   perm   = seg + NP;                           // NP ints
    int*   hist   = perm + NP;                          // NBLK*NS ints (4.6 MB)
    int*   total  = hist + (size_t)NBLK * NS;           // NS ints
    int*   starts = total + NS;                         // NS+1 ints

    mix_kernel<<<1, 64, 0, stream>>>(sw, bw, cm, M);
    prep_kernel<<<NBLK, 256, 0, stream>>>(unaries, sp_map, smA, seg);
    lhist_kernel<<<NBLK, 256, 0, stream>>>(seg, hist);
    colscan_kernel<<<NS, 256, 0, stream>>>(hist, total);
    binscan_kernel<<<1, 512, 0, stream>>>(total, starts);
    scatter2_kernel<<<NBLK, 256, 0, stream>>>(seg, hist, starts, perm);

    float* cur = smA;
    float* nxt = smB;
    for (int it = 0; it < NITER; it++) {
        k2_accum<<<NS, 256, 0, stream>>>(cur, perm, starts, B);
        k3_update<<<2048, 256, 0, stream>>>(unaries, cur, seg, B, lw, hw, M,
                                            nxt, out, (it == NITER - 1) ? 1 : 0);
        float* t = cur; cur = nxt; nxt = t;
    }
}

// Round 11
// 120.966 us; speedup vs baseline: 4.8669x; 2.0789x over previous
//
#include <hip/hip_runtime.h>
#include <math.h>

#define NC 6
#define NS 500
#define HWD 768
#define NP (HWD*HWD)
#define NBLK (NP/256)        // 2304 blocks of 256 pixels (exact)
#define EPSF 1e-5f
#define NITER 5
#define TBL (NS*NC)

// ---------------------------------------------------------------------------
// mix_kernel: M = compat @ (spatial_w + bilateral_w);  flag = all(lw==hw)
// flag==1 => cont update is exactly hw0+hw1 for every pixel (lw-hw factor = 0)
// ---------------------------------------------------------------------------
__global__ void mix_kernel(const float* __restrict__ sw, const float* __restrict__ bw,
                           const float* __restrict__ cm, const float* __restrict__ lw,
                           const float* __restrict__ hw,
                           float* __restrict__ M, int* __restrict__ flag) {
    int i = threadIdx.x;
    if (i < NC * NC) {
        int c = i / NC, k = i % NC;
        float acc = 0.f;
        #pragma unroll
        for (int j = 0; j < NC; j++) acc += cm[c * NC + j] * (sw[j * NC + k] + bw[j * NC + k]);
        M[i] = acc;
    }
    if (i == 0) {
        int f = 1;
        for (int c = 0; c < NC; c++) {
            if (lw[c] != hw[0]) f = 0;
            if (lw[NC + c] != hw[1]) f = 0;
        }
        flag[0] = f;
    }
}

// ---------------------------------------------------------------------------
// fused_fast: flag==1 path. Whole 5-iteration CRF recurrence per pixel in regs.
// q <- u - M@softmax(q) - (hw0+hw1)
// ---------------------------------------------------------------------------
__global__ __launch_bounds__(256) void fused_fast(const float* __restrict__ unaries,
                                                  const float* __restrict__ hw,
                                                  const float* __restrict__ M,
                                                  const int* __restrict__ flag,
                                                  float* __restrict__ out) {
    if (flag[0] == 0) return;
    __shared__ float sM[NC * NC];
    __shared__ float sc2;
    if (threadIdx.x < NC * NC) sM[threadIdx.x] = M[threadIdx.x];
    if (threadIdx.x == 0) sc2 = hw[0] + hw[1];
    __syncthreads();

    int p = blockIdx.x * 256 + threadIdx.x;
    const float2* u2 = (const float2*)(unaries + (size_t)p * NC);
    float2 a0 = u2[0], a1 = u2[1], a2 = u2[2];
    float uu[NC] = {a0.x, a0.y, a1.x, a1.y, a2.x, a2.y};
    float q[NC];
    #pragma unroll
    for (int c = 0; c < NC; c++) q[c] = uu[c];
    float c2 = sc2;

    #pragma unroll
    for (int it = 0; it < NITER; it++) {
        float m = q[0];
        #pragma unroll
        for (int c = 1; c < NC; c++) m = fmaxf(m, q[c]);
        float v[NC];
        float s = 0.f;
        #pragma unroll
        for (int c = 0; c < NC; c++) { v[c] = expf(q[c] - m); s += v[c]; }
        float inv = 1.f / s;
        #pragma unroll
        for (int c = 0; c < NC; c++) v[c] *= inv;
        #pragma unroll
        for (int c = 0; c < NC; c++) {
            float pw = 0.f;
            #pragma unroll
            for (int k = 0; k < NC; k++) pw += sM[c * NC + k] * v[k];
            q[c] = uu[c] - pw - c2;
        }
    }
    float2* o2 = (float2*)(out + (size_t)p * NC);
    o2[0] = make_float2(q[0], q[1]);
    o2[1] = make_float2(q[2], q[3]);
    o2[2] = make_float2(q[4], q[5]);
}

// ===========================================================================
// Generic path (flag==0): identical to Round-10 structure, each kernel guarded
// ===========================================================================

__global__ __launch_bounds__(256) void prep_kernel(const float* __restrict__ unaries,
                                                   const int* __restrict__ sp_map,
                                                   const int* __restrict__ flag,
                                                   float* __restrict__ sm,
                                                   int* __restrict__ seg) {
    if (flag[0]) return;
    int p = blockIdx.x * blockDim.x + threadIdx.x;
    if (p >= NP) return;
    int h = p / HWD;
    int w = p - h * HWD;
    seg[p] = sp_map[w * HWD + h];

    const float2* u2 = (const float2*)(unaries + (size_t)p * NC);
    float2 a0 = u2[0], a1 = u2[1], a2 = u2[2];
    float v[NC] = {a0.x, a0.y, a1.x, a1.y, a2.x, a2.y};
    float m = v[0];
    #pragma unroll
    for (int c = 1; c < NC; c++) m = fmaxf(m, v[c]);
    float s = 0.f;
    #pragma unroll
    for (int c = 0; c < NC; c++) { v[c] = expf(v[c] - m); s += v[c]; }
    float inv = 1.f / s;
    float2* o2 = (float2*)(sm + (size_t)p * NC);
    o2[0] = make_float2(v[0] * inv, v[1] * inv);
    o2[1] = make_float2(v[2] * inv, v[3] * inv);
    o2[2] = make_float2(v[4] * inv, v[5] * inv);
}

__global__ __launch_bounds__(256) void lhist_kernel(const int* __restrict__ seg,
                                                    const int* __restrict__ flag,
                                                    int* __restrict__ hist) {
    if (flag[0]) return;
    __shared__ int h[NS];
    int tid = threadIdx.x;
    for (int s = tid; s < NS; s += 256) h[s] = 0;
    __syncthreads();
    int p = blockIdx.x * 256 + tid;
    int s = seg[p];
    if (s >= 0 && s < NS) atomicAdd(&h[s], 1);
    __syncthreads();
    int* row = hist + (size_t)blockIdx.x * NS;
    for (int s = tid; s < NS; s += 256) row[s] = h[s];
}

__global__ __launch_bounds__(256) void colscan_kernel(const int* __restrict__ flag,
                                                      int* __restrict__ hist,
                                                      int* __restrict__ total) {
    if (flag[0]) return;
    int s = blockIdx.x, tid = threadIdx.x;
    int loc[9];
    int sum = 0;
    #pragma unroll
    for (int j = 0; j < 9; j++) {
        loc[j] = hist[(size_t)(tid * 9 + j) * NS + s];
        sum += loc[j];
    }
    __shared__ int A[256], Bf[256];
    A[tid] = sum;
    __syncthreads();
    int* src = A; int* dst = Bf;
    for (int off = 1; off < 256; off <<= 1) {
        int v = src[tid];
        if (tid >= off) v += src[tid - off];
        dst[tid] = v;
        __syncthreads();
        int* t = src; src = dst; dst = t;
    }
    int incl = src[tid];
    int run = incl - sum;
    #pragma unroll
    for (int j = 0; j < 9; j++) {
        int v = loc[j];
        hist[(size_t)(tid * 9 + j) * NS + s] = run;
        run += v;
    }
    if (tid == 255) total[s] = run;
}

__global__ __launch_bounds__(512) void binscan_kernel(const int* __restrict__ flag,
                                                      const int* __restrict__ total,
                                                      int* __restrict__ starts) {
    if (flag[0]) return;
    __shared__ int A[512], Bf[512];
    int tid = threadIdx.x;
    int own = (tid < NS) ? total[tid] : 0;
    A[tid] = own;
    __syncthreads();
    int* src = A; int* dst = Bf;
    for (int off = 1; off < 512; off <<= 1) {
        int v = src[tid];
        if (tid >= off) v += src[tid - off];
        dst[tid] = v;
        __syncthreads();
        int* t = src; src = dst; dst = t;
    }
    int incl = src[tid];
    if (tid < NS) starts[tid] = incl - own;
    if (tid == NS - 1) starts[NS] = incl;
}

__global__ __launch_bounds__(256) void scatter2_kernel(const int* __restrict__ seg,
                                                       const int* __restrict__ hist,
                                                       const int* __restrict__ starts,
                                                       const int* __restrict__ flag,
                                                       int* __restrict__ perm) {
    if (flag[0]) return;
    __shared__ int cur[NS];
    int tid = threadIdx.x;
    const int* row = hist + (size_t)blockIdx.x * NS;
    for (int s = tid; s < NS; s += 256) cur[s] = starts[s] + row[s];
    __syncthreads();
    int p = blockIdx.x * 256 + tid;
    int s = seg[p];
    if (s >= 0 && s < NS) {
        int idx = atomicAdd(&cur[s], 1);
        perm[idx] = p;
    }
}

__global__ __launch_bounds__(256) void k2_accum(const float* __restrict__ sm,
                                                const int* __restrict__ perm,
                                                const int* __restrict__ starts,
                                                const int* __restrict__ flag,
                                                float* __restrict__ B) {
    if (flag[0]) return;
    int s = blockIdx.x;
    int lo = starts[s], hi = starts[s + 1];
    int tid = threadIdx.x;
    float asp[NC] = {0.f, 0.f, 0.f, 0.f, 0.f, 0.f};
    float aco[NC] = {0.f, 0.f, 0.f, 0.f, 0.f, 0.f};

    for (int i = lo + tid; i < hi; i += 256) {
        int p = perm[i];
        const float2* s2 = (const float2*)(sm + (size_t)p * NC);
        float2 a0 = s2[0], a1 = s2[1], a2 = s2[2];
        float v[NC] = {a0.x, a0.y, a1.x, a1.y, a2.x, a2.y};
        float mx = v[0];
        #pragma unroll
        for (int c = 1; c < NC; c++) mx = fmaxf(mx, v[c]);
        float maxq = mx + EPSF;
        #pragma unroll
        for (int c = 0; c < NC; c++) {
            asp[c] += logf(v[c] + EPSF);
            float a = v[c] + EPSF + maxq - ((v[c] == mx) ? v[c] : 0.f);
            aco[c] += logf(a);
        }
    }
    #pragma unroll
    for (int c = 0; c < NC; c++) {
        #pragma unroll
        for (int off = 1; off < 64; off <<= 1) {
            asp[c] += __shfl_xor(asp[c], off, 64);
            aco[c] += __shfl_xor(aco[c], off, 64);
        }
    }
    __shared__ float red[4][2 * NC];
    int wid = tid >> 6, lane = tid & 63;
    if (lane == 0) {
        #pragma unroll
        for (int c = 0; c < NC; c++) { red[wid][c] = asp[c]; red[wid][NC + c] = aco[c]; }
    }
    __syncthreads();
    if (tid < 2 * NC) {
        float sum = red[0][tid] + red[1][tid] + red[2][tid] + red[3][tid];
        if (tid < NC) B[s * NC + tid] = sum;
        else          B[TBL + s * NC + (tid - NC)] = sum;
    }
}

__global__ __launch_bounds__(256) void k3_update(const float* __restrict__ unaries,
                                                 const float* __restrict__ sm,
                                                 const int* __restrict__ seg,
                                                 const float* __restrict__ B,
                                                 const float* __restrict__ low_w,
                                                 const float* __restrict__ high_w,
                                                 const float* __restrict__ M,
                                                 const int* __restrict__ flag,
                                                 float* __restrict__ sm_next,
                                                 float* __restrict__ out,
                                                 int writeOut) {
    if (flag[0]) return;
    __shared__ float sM[NC * NC];
    __shared__ float slw[2 * NC];
    __shared__ float shw[2];
    if (threadIdx.x < NC * NC) sM[threadIdx.x] = M[threadIdx.x];
    if (threadIdx.x < 2 * NC) slw[threadIdx.x] = low_w[threadIdx.x];
    if (threadIdx.x < 2) shw[threadIdx.x] = high_w[threadIdx.x];
    __syncthreads();

    int stride = gridDim.x * blockDim.x;
    for (int p = blockIdx.x * blockDim.x + threadIdx.x; p < NP; p += stride) {
        const float2* s2 = (const float2*)(sm + (size_t)p * NC);
        float2 a0 = s2[0], a1 = s2[1], a2 = s2[2];
        float v[NC] = {a0.x, a0.y, a1.x, a1.y, a2.x, a2.y};

        int sg = seg[p];
        bool inr = (sg >= 0 && sg < NS);
        int sc = inr ? sg : (sg < 0 ? 0 : NS - 1);
        float fin = inr ? 1.f : 0.f;

        float mx = v[0];
        #pragma unroll
        for (int c = 1; c < NC; c++) mx = fmaxf(mx, v[c]);
        float maxq = mx + EPSF;

        const float2* bsp2 = (const float2*)(B + (size_t)sc * NC);
        const float2* bco2 = (const float2*)(B + TBL + (size_t)sc * NC);
        float2 p0 = bsp2[0], p1 = bsp2[1], p2 = bsp2[2];
        float2 c0 = bco2[0], c1 = bco2[1], c2 = bco2[2];
        float psp[NC] = {p0.x, p0.y, p1.x, p1.y, p2.x, p2.y};
        float pio[NC] = {c0.x, c0.y, c1.x, c1.y, c2.x, c2.y};

        float cont[NC];
        #pragma unroll
        for (int c = 0; c < NC; c++) {
            float ps = psp[c] * fin;
            float pi = pio[c] * fin;
            float a = v[c] + EPSF + maxq - ((v[c] == mx) ? v[c] : 0.f);
            float qvs = a * fin;
            qvs += (qvs == 0.f) ? 1.f : 0.f;
            float qmod = v[c] + ((v[c] == 0.f) ? 1.f : 0.f);
            float ftsp = expf(ps - logf(qmod + EPSF));
            float spu = slw[c] * ftsp + shw[0] * (1.f - ftsp);
            float ftc = expf(pi - logf(qvs + EPSF));
            float cu = slw[NC + c] * ftc + shw[1] * (1.f - ftc);
            cont[c] = spu + cu;
        }

        const float2* u2 = (const float2*)(unaries + (size_t)p * NC);
        float2 u0 = u2[0], u1 = u2[1], u2v = u2[2];
        float uu[NC] = {u0.x, u0.y, u1.x, u1.y, u2v.x, u2v.y};

        float qn[NC];
        #pragma unroll
        for (int c = 0; c < NC; c++) {
            float pw = 0.f;
            #pragma unroll
            for (int k = 0; k < NC; k++) pw += sM[c * NC + k] * v[k];
            qn[c] = uu[c] - pw - cont[c];
        }

        if (writeOut) {
            float2* o2 = (float2*)(out + (size_t)p * NC);
            o2[0] = make_float2(qn[0], qn[1]);
            o2[1] = make_float2(qn[2], qn[3]);
            o2[2] = make_float2(qn[4], qn[5]);
        } else {
            float m2 = qn[0];
            #pragma unroll
            for (int c = 1; c < NC; c++) m2 = fmaxf(m2, qn[c]);
            float ssum = 0.f;
            #pragma unroll
            for (int c = 0; c < NC; c++) { qn[c] = expf(qn[c] - m2); ssum += qn[c]; }
            float inv = 1.f / ssum;
            float2* o2 = (float2*)(sm_next + (size_t)p * NC);
            o2[0] = make_float2(qn[0] * inv, qn[1] * inv);
            o2[1] = make_float2(qn[2] * inv, qn[3] * inv);
            o2[2] = make_float2(qn[4] * inv, qn[5] * inv);
        }
    }
}

extern "C" void kernel_launch(void* const* d_in, const int* in_sizes, int n_in,
                              void* d_out, int out_size, void* d_ws, size_t ws_size,
                              hipStream_t stream) {
    const float* unaries = (const float*)d_in[0];
    // d_in[1] = rgb (unused: high_dim_filter replaced by identity)
    const int* sp_map   = (const int*)d_in[2];
    const float* sw     = (const float*)d_in[3];
    const float* bw     = (const float*)d_in[4];
    const float* cm     = (const float*)d_in[5];
    const float* lw     = (const float*)d_in[6];
    const float* hw     = (const float*)d_in[7];
    float* out = (float*)d_out;

    float* smA    = (float*)d_ws;                       // NP*NC floats
    float* smB    = smA + (size_t)NP * NC;              // NP*NC floats
    float* B      = smB + (size_t)NP * NC;              // 2*TBL floats
    float* M      = B + 2 * TBL;                        // 36 floats
    int*   seg    = (int*)(M + NC * NC);                // NP ints
    int*   perm   = seg + NP;                           // NP ints
    int*   hist   = perm + NP;                          // NBLK*NS ints (4.6 MB)
    int*   total  = hist + (size_t)NBLK * NS;           // NS ints
    int*   starts = total + NS;                         // NS+1 ints
    int*   flag   = starts + NS + 2;                    // 1 int

    mix_kernel<<<1, 64, 0, stream>>>(sw, bw, cm, lw, hw, M, flag);
    // fast path (exact when low_w==high_w broadcast: cont == hw0+hw1 identically)
    fused_fast<<<NBLK, 256, 0, stream>>>(unaries, hw, M, flag, out);
    // generic path (each kernel early-outs when flag==1)
    prep_kernel<<<NBLK, 256, 0, stream>>>(unaries, sp_map, flag, smA, seg);
    lhist_kernel<<<NBLK, 256, 0, stream>>>(seg, flag, hist);
    colscan_kernel<<<NS, 256, 0, stream>>>(flag, hist, total);
    binscan_kernel<<<1, 512, 0, stream>>>(flag, total, starts);
    scatter2_kernel<<<NBLK, 256, 0, stream>>>(seg, hist, starts, flag, perm);

    float* cur = smA;
    float* nxt = smB;
    for (int it = 0; it < NITER; it++) {
        k2_accum<<<NS, 256, 0, stream>>>(cur, perm, starts, flag, B);
        k3_update<<<2048, 256, 0, stream>>>(unaries, cur, seg, B, lw, hw, M, flag,
                                            nxt, out, (it == NITER - 1) ? 1 : 0);
        float* t = cur; cur = nxt; nxt = t;
    }
}